// Round 4
// baseline (100.064 us; speedup 1.0000x reference)
//
#include <hip/hip_runtime.h>

typedef short short8 __attribute__((ext_vector_type(8)));
typedef float f32x4 __attribute__((ext_vector_type(4)));
typedef unsigned int u32;
typedef unsigned short u16;

union PackU { u32 u[4]; short8 s8; };

__device__ __forceinline__ u16 f2bf(float f) {
  unsigned u = __builtin_bit_cast(unsigned, f);
  u = (u + 0x7FFFu + ((u >> 16) & 1u)) >> 16;
  return (u16)u;
}

__device__ __forceinline__ u32 cvt_pk_bf16(float lo, float hi) {
  u32 r;
  asm("v_cvt_pk_bf16_f32 %0, %1, %2" : "=v"(r) : "v"(lo), "v"(hi));
  return r;
}

__device__ __forceinline__ f32x4 mfma16(short8 a, short8 b, f32x4 c) {
  return __builtin_amdgcn_mfma_f32_16x16x32_bf16(a, b, c, 0, 0, 0);
}

// scale for Wq: (1/sqrt(1024)) * log2(e)  -> scores come out in log2 domain
#define QSCALE 0.04508422619125366f

// ---------------------------------------------------------------------------
// W conversion: wcat[192][1024] bf16. rows 0..63 = Wq*QSCALE, 64..127 = Wk,
// 128..191 = Wv.  grid 96 x 256, 8 elems/thread.
// ---------------------------------------------------------------------------
__global__ __launch_bounds__(256) void wconv_kernel(
    const float* __restrict__ Wk, const float* __restrict__ Wq,
    const float* __restrict__ Wv, u16* __restrict__ wcat)
{
  const int t = blockIdx.x * 256 + threadIdx.x;   // 24576 threads
  const int row = t >> 7;
  const int col = (t & 127) * 8;
  const float* src;
  float scale = 1.0f;
  if (row < 64)       { src = Wq + (size_t)row * 1024;        scale = QSCALE; }
  else if (row < 128) { src = Wk + (size_t)(row - 64) * 1024; }
  else                { src = Wv + (size_t)(row - 128) * 1024; }
  float4 a = *(const float4*)(src + col);
  float4 b = *(const float4*)(src + col + 4);
  PackU p;
  p.u[0] = cvt_pk_bf16(a.x * scale, a.y * scale);
  p.u[1] = cvt_pk_bf16(a.z * scale, a.w * scale);
  p.u[2] = cvt_pk_bf16(b.x * scale, b.y * scale);
  p.u[3] = cvt_pk_bf16(b.z * scale, b.w * scale);
  *(short8*)&wcat[(size_t)row * 1024 + col] = p.s8;
}

// ---------------------------------------------------------------------------
// Projection: 512 blocks x 512 thr = 8 independent waves (2 row x 4 col).
// Block = 32 rows x 192 cols; wave = 16 rows x 48 cols. NO LDS, NO BARRIERS.
// W frags loaded per-lane straight from L2-resident wcat; x loaded fp32 and
// packed with v_cvt_pk_bf16_f32. Both register-prefetched one K-step ahead
// (named even/odd buffers -> counted vmcnt, never drained).
// Outputs: qw,kw [8][2048][64] bf16; vtw [8][64][2048] bf16 in PERMUTED
// key order: within each 32-token block, token t stored at
// (lg<<3)|(sub<<2)|r  where lg=(t>>2)&3, sub=(t>>4)&1, r=t&3.
// ---------------------------------------------------------------------------
__global__ __launch_bounds__(512, 4) void proj_kernel(
    const float* __restrict__ x, const u16* __restrict__ wcat,
    u16* __restrict__ qw, u16* __restrict__ kw, u16* __restrict__ vtw)
{
  const int tid  = threadIdx.x;
  const int lane = tid & 63;
  const int w    = tid >> 6;
  const int lr   = lane & 15, lg = lane >> 4;
  const int wr   = w >> 2, wc = w & 3;
  const int row0 = blockIdx.x * 32;

  const float* xp = x    + (size_t)(row0 + wr * 16 + lr) * 1024 + lg * 8;
  const u16*   wp = wcat + (size_t)(wc * 48 + lr) * 1024 + lg * 8;

  const f32x4 vzero = {0.f, 0.f, 0.f, 0.f};
  f32x4 acc[3];
  acc[0] = vzero; acc[1] = vzero; acc[2] = vzero;

  float4 xA0, xA1, xA2, xA3, xB0, xB1, xB2, xB3;
  short8 wA0, wA1, wA2, wA3, wA4, wA5, wB0, wB1, wB2, wB3, wB4, wB5;

#define XLD(P, k0)                                 \
  P##0 = *(const float4*)(xp + (k0));              \
  P##1 = *(const float4*)(xp + (k0) + 4);          \
  P##2 = *(const float4*)(xp + (k0) + 32);         \
  P##3 = *(const float4*)(xp + (k0) + 36);

#define WLD(P, k0)                                           \
  P##0 = *(const short8*)(wp + (k0));                        \
  P##1 = *(const short8*)(wp + (k0) + 32);                   \
  P##2 = *(const short8*)(wp + 16384 + (k0));                \
  P##3 = *(const short8*)(wp + 16384 + (k0) + 32);           \
  P##4 = *(const short8*)(wp + 32768 + (k0));                \
  P##5 = *(const short8*)(wp + 32768 + (k0) + 32);

#define STEP(XP, WP)                                          \
  {                                                           \
    PackU p0, p1;                                             \
    p0.u[0] = cvt_pk_bf16((XP##0).x, (XP##0).y);              \
    p0.u[1] = cvt_pk_bf16((XP##0).z, (XP##0).w);              \
    p0.u[2] = cvt_pk_bf16((XP##1).x, (XP##1).y);              \
    p0.u[3] = cvt_pk_bf16((XP##1).z, (XP##1).w);              \
    p1.u[0] = cvt_pk_bf16((XP##2).x, (XP##2).y);              \
    p1.u[1] = cvt_pk_bf16((XP##2).z, (XP##2).w);              \
    p1.u[2] = cvt_pk_bf16((XP##3).x, (XP##3).y);              \
    p1.u[3] = cvt_pk_bf16((XP##3).z, (XP##3).w);              \
    acc[0] = mfma16(p0.s8, WP##0, acc[0]);                    \
    acc[0] = mfma16(p1.s8, WP##1, acc[0]);                    \
    acc[1] = mfma16(p0.s8, WP##2, acc[1]);                    \
    acc[1] = mfma16(p1.s8, WP##3, acc[1]);                    \
    acc[2] = mfma16(p0.s8, WP##4, acc[2]);                    \
    acc[2] = mfma16(p1.s8, WP##5, acc[2]);                    \
  }

  XLD(xA, 0)
  WLD(wA, 0)
  for (int i = 0; i < 8; ++i) {
    const int k0 = i * 128;
    XLD(xB, k0 + 64)
    WLD(wB, k0 + 64)
    STEP(xA, wA)
    if (i < 7) {
      XLD(xA, k0 + 128)
      WLD(wA, k0 + 128)
    }
    STEP(xB, wB)
  }
#undef XLD
#undef WLD
#undef STEP

  const int bb  = row0 >> 11;
  const int tb  = row0 & 2047;
  const int tl0 = tb + wr * 16 + 4 * lg;
#pragma unroll
  for (int c = 0; c < 3; ++c) {
    const int n  = wc * 48 + c * 16 + lr;
    const int hd = n & 63;
    if (n < 128) {
      u16* dst = (n < 64) ? qw : kw;
#pragma unroll
      for (int r = 0; r < 4; ++r)
        dst[((size_t)(bb * 2048 + tl0 + r)) * 64 + hd] = f2bf(acc[c][r]);
    } else {
      const int posb = (tl0 & ~31) | (((tl0 >> 2) & 3) << 3) | (((tl0 >> 4) & 1) << 2);
      u32* dst = (u32*)&vtw[((size_t)(bb * 64 + hd)) * 2048 + posb];
      dst[0] = cvt_pk_bf16(acc[c][0], acc[c][1]);
      dst[1] = cvt_pk_bf16(acc[c][2], acc[c][3]);
    }
  }
}

// ---------------------------------------------------------------------------
// Attention partials. grid = 8 batches x 80 (group,chunk) blocks, 256 thr.
// Block = q-group j (64 rows = 4 waves x 16-row strips), KV chunk of <=8
// 64-key tiles staged in LDS (dbuf, XOR-swizzled), shared by the 4 waves.
// Swapped QK (A=K, B=Q): lane holds S[key=16c+4lg+r][q=lr]. Static-max
// softmax: P = exp2(S) (Wq pre-scaled by log2e/32), per-lane scalar lsum.
// PV: A=V(perm layout), B=P packed lane-locally. Chunked groups write
// unnormalized partials; single-chunk groups (j<8) write out directly.
// ---------------------------------------------------------------------------
__global__ __launch_bounds__(256, 2) void attn_kernel(
    const u16* __restrict__ qw, const u16* __restrict__ kw,
    const u16* __restrict__ vtw, float* __restrict__ out,
    float* __restrict__ Opart, float* __restrict__ lpart)
{
  const int tid  = threadIdx.x;
  const int lane = tid & 63;
  const int sid  = tid >> 6;           // strip 0..3
  const int lr   = lane & 15, lg = lane >> 4;
  const int bid  = blockIdx.x;
  const int b    = bid / 80;
  const int g    = bid % 80;

  int j, ch, nch;
  if (g < 8)       { j = g;                ch = 0;          nch = 1; }
  else if (g < 24) { int u = g - 8;  j = 8  + (u >> 1); ch = u & 1;  nch = 2; }
  else if (g < 48) { int u = g - 24; j = 16 + u / 3;    ch = u % 3;  nch = 3; }
  else             { int u = g - 48; j = 24 + (u >> 2); ch = u & 3;  nch = 4; }
  const int kt0 = ch * 8;
  const int kt1 = (kt0 + 8 < j + 1) ? (kt0 + 8) : (j + 1);
  const int q0r = j * 64 + sid * 16;

  __shared__ u16 lK[2][64 * 64];
  __shared__ u16 lV[2][64 * 64];

  const size_t qoff = ((size_t)(b * 2048 + q0r + lr)) * 64 + lg * 8;
  const short8 qa = *(const short8*)(qw + qoff);
  const short8 qb = *(const short8*)(qw + qoff + 32);

  const f32x4 vzero = {0.f, 0.f, 0.f, 0.f};
  f32x4 o[4];
#pragma unroll
  for (int i = 0; i < 4; ++i) o[i] = vzero;
  float lsum = 0.f;

  // staging geometry: 512 chunks per matrix, 2 per thread
  const int sr0 = tid >> 3;            // 0..31 (i=1 adds 32)
  const int sc0 = (tid & 7) * 8;
  const int la0 = (sr0 * 64 + sc0) ^ ((sr0 & 7) << 3);

  short8 kst[2], vst[2];
  {
    const int kb = kt0 * 64;
#pragma unroll
    for (int i = 0; i < 2; ++i) {
      const int r = sr0 + i * 32;
      kst[i] = *(const short8*)(kw  + ((size_t)(b * 2048 + kb + r)) * 64 + sc0);
      vst[i] = *(const short8*)(vtw + ((size_t)(b * 64 + r)) * 2048 + kb + sc0);
    }
#pragma unroll
    for (int i = 0; i < 2; ++i) {
      *(short8*)&lK[0][la0 + i * 2048] = kst[i];
      *(short8*)&lV[0][la0 + i * 2048] = vst[i];
    }
  }
  __syncthreads();

  for (int kt = kt0; kt < kt1; ++kt) {
    const int cur = (kt - kt0) & 1;
    if (kt + 1 < kt1) {
      const int kb = (kt + 1) * 64;
#pragma unroll
      for (int i = 0; i < 2; ++i) {
        const int r = sr0 + i * 32;
        kst[i] = *(const short8*)(kw  + ((size_t)(b * 2048 + kb + r)) * 64 + sc0);
        vst[i] = *(const short8*)(vtw + ((size_t)(b * 64 + r)) * 2048 + kb + sc0);
      }
    }
    // QK^T (swapped): s4[c][r] = S[key = 64kt+16c+4lg+r][q = q0r+lr]
    f32x4 s4[4];
#pragma unroll
    for (int c = 0; c < 4; ++c) {
      const int row = 16 * c + lr;
      const short8 kf0 = *(const short8*)&lK[cur][(row * 64 + lg * 8) ^ ((row & 7) << 3)];
      const short8 kf1 = *(const short8*)&lK[cur][(row * 64 + 32 + lg * 8) ^ ((row & 7) << 3)];
      f32x4 z = vzero;
      z = mfma16(kf0, qa, z);
      z = mfma16(kf1, qb, z);
      s4[c] = z;
    }
    if (kt == j) {   // causal mask on the diagonal tile
#pragma unroll
      for (int c = 0; c < 4; ++c)
#pragma unroll
        for (int r = 0; r < 4; ++r)
          if (16 * c + 4 * lg + r > sid * 16 + lr) s4[c][r] = -1e30f;
    }
    // exp2 + lane-local row-sum accumulation
#pragma unroll
    for (int c = 0; c < 4; ++c)
#pragma unroll
      for (int r = 0; r < 4; ++r) {
        const float e = __builtin_amdgcn_exp2f(s4[c][r]);
        s4[c][r] = e;
        lsum += e;
      }
    // pack P lane-locally: pb0 = keys of c=0,1 ; pb1 = keys of c=2,3
    PackU p0, p1;
    p0.u[0] = cvt_pk_bf16(s4[0][0], s4[0][1]);
    p0.u[1] = cvt_pk_bf16(s4[0][2], s4[0][3]);
    p0.u[2] = cvt_pk_bf16(s4[1][0], s4[1][1]);
    p0.u[3] = cvt_pk_bf16(s4[1][2], s4[1][3]);
    p1.u[0] = cvt_pk_bf16(s4[2][0], s4[2][1]);
    p1.u[1] = cvt_pk_bf16(s4[2][2], s4[2][3]);
    p1.u[2] = cvt_pk_bf16(s4[3][0], s4[3][1]);
    p1.u[3] = cvt_pk_bf16(s4[3][2], s4[3][3]);
    const short8 pb0 = p0.s8, pb1 = p1.s8;
    // PV: o[cd] over d = 16cd+4lg+r
#pragma unroll
    for (int cd = 0; cd < 4; ++cd) {
      const int row = 16 * cd + lr;
      const short8 vf0 = *(const short8*)&lV[cur][(row * 64 + lg * 8) ^ ((row & 7) << 3)];
      const short8 vf1 = *(const short8*)&lV[cur][(row * 64 + 32 + lg * 8) ^ ((row & 7) << 3)];
      o[cd] = mfma16(vf0, pb0, o[cd]);
      o[cd] = mfma16(vf1, pb1, o[cd]);
    }
    if (kt + 1 < kt1) {
#pragma unroll
      for (int i = 0; i < 2; ++i) {
        *(short8*)&lK[cur ^ 1][la0 + i * 2048] = kst[i];
        *(short8*)&lV[cur ^ 1][la0 + i * 2048] = vst[i];
      }
      __syncthreads();
    }
  }

  lsum += __shfl_xor(lsum, 16, 64);
  lsum += __shfl_xor(lsum, 32, 64);

  if (nch == 1) {
    const float inv = 1.0f / lsum;
    float* op = out + ((size_t)(b * 2048 + q0r + lr)) * 64;
#pragma unroll
    for (int cd = 0; cd < 4; ++cd) {
      f32x4 v = o[cd] * inv;
      *(f32x4*)(op + 16 * cd + 4 * lg) = v;
    }
  } else {
    int pb;
    if (j < 16)      pb = 2 * (j - 8);
    else if (j < 24) pb = 16 + 3 * (j - 16);
    else             pb = 40 + 4 * (j - 24);
    const int pidx = b * 72 + pb + ch;
    float* op = Opart + ((size_t)(pidx * 64) + sid * 16 + lr) * 64;
#pragma unroll
    for (int cd = 0; cd < 4; ++cd)
      *(f32x4*)(op + 16 * cd + 4 * lg) = o[cd];
    if (lg == 0) lpart[pidx * 64 + sid * 16 + lr] = lsum;
  }
}

// ---------------------------------------------------------------------------
// Merge partials for chunked groups (j >= 8). 768 blocks x 256 thr.
// thread -> (merged q-row, 4-wide d quad); out = sum(Opart)/sum(l).
// ---------------------------------------------------------------------------
__global__ __launch_bounds__(256) void merge_kernel(
    const float* __restrict__ Opart, const float* __restrict__ lpart,
    float* __restrict__ out)
{
  const int t = blockIdx.x * 256 + threadIdx.x;
  const int ridx = t >> 4;           // 0..12287
  const int dq = (t & 15) * 4;
  const int b = ridx / 1536;
  const int r2 = ridx % 1536;
  const int jj = r2 >> 6;            // 0..23 -> j = jj+8
  const int ql = r2 & 63;
  int pb, nch;
  if (jj < 8)       { pb = 2 * jj;            nch = 2; }
  else if (jj < 16) { pb = 16 + 3 * (jj - 8); nch = 3; }
  else              { pb = 40 + 4 * (jj - 16); nch = 4; }
  const int base = b * 72 + pb;
  f32x4 acc = {0.f, 0.f, 0.f, 0.f};
  float l = 0.f;
  for (int c = 0; c < nch; ++c) {
    acc += *(const f32x4*)(Opart + (((size_t)(base + c) * 64 + ql) * 64 + dq));
    l += lpart[(base + c) * 64 + ql];
  }
  const float inv = 1.0f / l;
  *(f32x4*)&out[((size_t)(b * 2048 + (jj + 8) * 64 + ql)) * 64 + dq] = acc * inv;
}

extern "C" void kernel_launch(void* const* d_in, const int* in_sizes, int n_in,
                              void* d_out, int out_size, void* d_ws, size_t ws_size,
                              hipStream_t stream) {
  // setup_inputs order: x, Wk, Wq, Wv
  const float* x  = (const float*)d_in[0];
  const float* Wk = (const float*)d_in[1];
  const float* Wq = (const float*)d_in[2];
  const float* Wv = (const float*)d_in[3];

  u16* wcat = (u16*)d_ws;                        // 192*1024       = 196608
  u16* qw   = wcat + 196608;                     // 16384*64
  u16* kw   = qw + 1048576;
  u16* vtw  = kw + 1048576;
  float* Opart = (float*)(vtw + 1048576);        // 576*64*64 f32
  float* lpart = Opart + 2359296;                // 576*64 f32
  float* out = (float*)d_out;

  wconv_kernel<<<dim3(96),  dim3(256), 0, stream>>>(Wk, Wq, Wv, wcat);
  proj_kernel <<<dim3(512), dim3(512), 0, stream>>>(x, wcat, qw, kw, vtw);
  attn_kernel <<<dim3(640), dim3(256), 0, stream>>>(qw, kw, vtw, out, Opart, lpart);
  merge_kernel<<<dim3(768), dim3(256), 0, stream>>>(Opart, lpart, out);
}

// Round 5
// 40.474 us; speedup vs baseline: 2.4723x; 2.4723x over previous
//
#include <hip/hip_runtime.h>

typedef short short8 __attribute__((ext_vector_type(8)));
typedef float f32x4 __attribute__((ext_vector_type(4)));
typedef unsigned int u32;
typedef unsigned short u16;

union PackU { u32 u[4]; short8 s8; };

__device__ __forceinline__ u16 f2bf(float f) {
  unsigned u = __builtin_bit_cast(unsigned, f);
  u = (u + 0x7FFFu + ((u >> 16) & 1u)) >> 16;
  return (u16)u;
}

__device__ __forceinline__ u32 cvt_pk_bf16(float lo, float hi) {
  u32 r;
  asm("v_cvt_pk_bf16_f32 %0, %1, %2" : "=v"(r) : "v"(lo), "v"(hi));
  return r;
}

__device__ __forceinline__ f32x4 mfma16(short8 a, short8 b, f32x4 c) {
  return __builtin_amdgcn_mfma_f32_16x16x32_bf16(a, b, c, 0, 0, 0);
}

// scale for Wq: (1/sqrt(1024)) * log2(e)  -> scores come out in log2 domain
#define QSCALE 0.04508422619125366f

// ---------------------------------------------------------------------------
// W conversion: wcat[192][1024] bf16. rows 0..63 = Wq*QSCALE, 64..127 = Wk,
// 128..191 = Wv.  grid 96 x 256, 8 elems/thread.
// ---------------------------------------------------------------------------
__global__ __launch_bounds__(256) void wconv_kernel(
    const float* __restrict__ Wk, const float* __restrict__ Wq,
    const float* __restrict__ Wv, u16* __restrict__ wcat)
{
  const int t = blockIdx.x * 256 + threadIdx.x;   // 24576 threads
  const int row = t >> 7;
  const int col = (t & 127) * 8;
  const float* src;
  float scale = 1.0f;
  if (row < 64)       { src = Wq + (size_t)row * 1024;        scale = QSCALE; }
  else if (row < 128) { src = Wk + (size_t)(row - 64) * 1024; }
  else                { src = Wv + (size_t)(row - 128) * 1024; }
  float4 a = *(const float4*)(src + col);
  float4 b = *(const float4*)(src + col + 4);
  PackU p;
  p.u[0] = cvt_pk_bf16(a.x * scale, a.y * scale);
  p.u[1] = cvt_pk_bf16(a.z * scale, a.w * scale);
  p.u[2] = cvt_pk_bf16(b.x * scale, b.y * scale);
  p.u[3] = cvt_pk_bf16(b.z * scale, b.w * scale);
  *(short8*)&wcat[(size_t)row * 1024 + col] = p.s8;
}

// ---------------------------------------------------------------------------
// Projection: 256 blocks x 512 thr (8 waves, 2 row-groups x 4 col-groups).
// Block = 64 tokens x 192 heads; wave = 32 tokens x 48 heads. BK=64.
// x AND W staged through double-buffered LDS via registers; x converted
// f32->bf16 in-flight (cvt_pk). Depth-2 prefetch: step s issues loads for
// s+2, commits regs of s+1 to LDS after MFMAs, one barrier per step.
// Loads stay in flight across barriers (counted vmcnt).
// Outputs: qw,kw [8][2048][64] bf16; vtw [8][64][2048] bf16 in PERMUTED
// key order: within each 32-token block, token t stored at
// (lg<<3)|(sub<<2)|r  where lg=(t>>2)&3, sub=(t>>4)&1, r=t&3.
// ---------------------------------------------------------------------------
struct Stage {
  float4 x0, x1;        // 8 fp32 of x
  short8 w0, w1, w2;    // 3 rows-chunks of W (r, r+64, r+128)
};

__global__ __launch_bounds__(512, 2) void proj_kernel(
    const float* __restrict__ x, const u16* __restrict__ wcat,
    u16* __restrict__ qw, u16* __restrict__ kw, u16* __restrict__ vtw)
{
  const int tid  = threadIdx.x;
  const int lane = tid & 63;
  const int w    = tid >> 6;
  const int lr   = lane & 15, lg = lane >> 4;
  const int wr   = w >> 2, wc = w & 3;   // 2x4 wave grid
  const int row0 = blockIdx.x * 64;

  __shared__ u16 lX[2][64 * 64];    // 2 x 8KB
  __shared__ u16 lW[2][192 * 64];   // 2 x 24KB

  // staging geometry: thread -> (row tid>>3, col (tid&7)*8)
  const int sr = tid >> 3;              // 0..63
  const int sc = (tid & 7) * 8;
  const float* xp = x    + (size_t)(row0 + sr) * 1024 + sc;
  const u16*   wp = wcat + (size_t)sr * 1024 + sc;
  const int sIdx = (sr * 64 + sc) ^ ((sr & 7) << 3);   // same swizzle all 3 W rows

  const f32x4 vzero = {0.f, 0.f, 0.f, 0.f};
  f32x4 acc[2][3];
#pragma unroll
  for (int m = 0; m < 2; ++m)
#pragma unroll
    for (int c = 0; c < 3; ++c) acc[m][c] = vzero;

  auto issue = [&](Stage& S, int k0) {
    S.x0 = *(const float4*)(xp + k0);
    S.x1 = *(const float4*)(xp + k0 + 4);
    S.w0 = *(const short8*)(wp + k0);
    S.w1 = *(const short8*)(wp + k0 + 65536);    // +64 rows
    S.w2 = *(const short8*)(wp + k0 + 131072);   // +128 rows
  };
  auto commit = [&](const Stage& S, int buf) {
    PackU p;
    p.u[0] = cvt_pk_bf16(S.x0.x, S.x0.y);
    p.u[1] = cvt_pk_bf16(S.x0.z, S.x0.w);
    p.u[2] = cvt_pk_bf16(S.x1.x, S.x1.y);
    p.u[3] = cvt_pk_bf16(S.x1.z, S.x1.w);
    *(short8*)&lX[buf][sIdx]        = p.s8;
    *(short8*)&lW[buf][sIdx]        = S.w0;
    *(short8*)&lW[buf][sIdx + 4096] = S.w1;
    *(short8*)&lW[buf][sIdx + 8192] = S.w2;
  };
  auto computeStep = [&](int buf) {
    short8 af[2][2], wf[3][2];
#pragma unroll
    for (int m = 0; m < 2; ++m) {
      const int ar = wr * 32 + m * 16 + lr;
#pragma unroll
      for (int ks = 0; ks < 2; ++ks)
        af[m][ks] = *(const short8*)&lX[buf][(ar * 64 + ks * 32 + lg * 8) ^ ((ar & 7) << 3)];
    }
#pragma unroll
    for (int c = 0; c < 3; ++c) {
      const int nr = wc * 48 + c * 16 + lr;
#pragma unroll
      for (int ks = 0; ks < 2; ++ks)
        wf[c][ks] = *(const short8*)&lW[buf][(nr * 64 + ks * 32 + lg * 8) ^ ((nr & 7) << 3)];
    }
#pragma unroll
    for (int m = 0; m < 2; ++m)
#pragma unroll
      for (int c = 0; c < 3; ++c) {
        acc[m][c] = mfma16(af[m][0], wf[c][0], acc[m][c]);
        acc[m][c] = mfma16(af[m][1], wf[c][1], acc[m][c]);
      }
  };

  Stage A, B;
  issue(A, 0);
  issue(B, 64);
  commit(A, 0);
  __syncthreads();

  for (int it = 0; it < 8; ++it) {
    const int s = 2 * it;
    // ---- even step s: LDS buf0 holds s; regB holds s+1 ----
    if (it < 7) issue(A, (s + 2) * 64);
    __builtin_amdgcn_sched_barrier(0);
    computeStep(0);
    commit(B, 1);
    __syncthreads();
    // ---- odd step s+1: LDS buf1 holds s+1; regA holds s+2 ----
    if (it < 7) issue(B, (s + 3) * 64);
    __builtin_amdgcn_sched_barrier(0);
    computeStep(1);
    if (it < 7) {
      commit(A, 0);
    }
    __syncthreads();
  }

  const int bb = row0 >> 11;
  const int tb = row0 & 2047;
#pragma unroll
  for (int m = 0; m < 2; ++m) {
    const int tl0 = tb + wr * 32 + 16 * m + 4 * lg;
#pragma unroll
    for (int c = 0; c < 3; ++c) {
      const int n  = wc * 48 + c * 16 + lr;
      const int hd = n & 63;
      if (n < 128) {
        u16* dst = (n < 64) ? qw : kw;
#pragma unroll
        for (int r = 0; r < 4; ++r)
          dst[((size_t)(bb * 2048 + tl0 + r)) * 64 + hd] = f2bf(acc[m][c][r]);
      } else {
        const int posb = (tl0 & ~31) | (((tl0 >> 2) & 3) << 3) | (((tl0 >> 4) & 1) << 2);
        u32* dst = (u32*)&vtw[((size_t)(bb * 64 + hd)) * 2048 + posb];
        dst[0] = cvt_pk_bf16(acc[m][c][0], acc[m][c][1]);
        dst[1] = cvt_pk_bf16(acc[m][c][2], acc[m][c][3]);
      }
    }
  }
}

// ---------------------------------------------------------------------------
// Attention partials. grid = 8 batches x 80 (group,chunk) blocks, 256 thr.
// Block = q-group j (64 rows = 4 waves x 16-row strips), KV chunk of <=8
// 64-key tiles staged in LDS (dbuf, XOR-swizzled), shared by the 4 waves.
// Swapped QK (A=K, B=Q): lane holds S[key=16c+4lg+r][q=lr]. Static-max
// softmax: P = exp2(S) (Wq pre-scaled by log2e/32), per-lane scalar lsum.
// PV: A=V(perm layout), B=P packed lane-locally. Chunked groups write
// unnormalized partials; single-chunk groups (j<8) write out directly.
// ---------------------------------------------------------------------------
__global__ __launch_bounds__(256, 2) void attn_kernel(
    const u16* __restrict__ qw, const u16* __restrict__ kw,
    const u16* __restrict__ vtw, float* __restrict__ out,
    float* __restrict__ Opart, float* __restrict__ lpart)
{
  const int tid  = threadIdx.x;
  const int lane = tid & 63;
  const int sid  = tid >> 6;           // strip 0..3
  const int lr   = lane & 15, lg = lane >> 4;
  const int bid  = blockIdx.x;
  const int b    = bid / 80;
  const int g    = bid % 80;

  int j, ch, nch;
  if (g < 8)       { j = g;                ch = 0;          nch = 1; }
  else if (g < 24) { int u = g - 8;  j = 8  + (u >> 1); ch = u & 1;  nch = 2; }
  else if (g < 48) { int u = g - 24; j = 16 + u / 3;    ch = u % 3;  nch = 3; }
  else             { int u = g - 48; j = 24 + (u >> 2); ch = u & 3;  nch = 4; }
  const int kt0 = ch * 8;
  const int kt1 = (kt0 + 8 < j + 1) ? (kt0 + 8) : (j + 1);
  const int q0r = j * 64 + sid * 16;

  __shared__ u16 lK[2][64 * 64];
  __shared__ u16 lV[2][64 * 64];

  const size_t qoff = ((size_t)(b * 2048 + q0r + lr)) * 64 + lg * 8;
  const short8 qa = *(const short8*)(qw + qoff);
  const short8 qb = *(const short8*)(qw + qoff + 32);

  const f32x4 vzero = {0.f, 0.f, 0.f, 0.f};
  f32x4 o[4];
#pragma unroll
  for (int i = 0; i < 4; ++i) o[i] = vzero;
  float lsum = 0.f;

  // staging geometry: 512 chunks per matrix, 2 per thread
  const int sr0 = tid >> 3;            // 0..31 (i=1 adds 32)
  const int sc0 = (tid & 7) * 8;
  const int la0 = (sr0 * 64 + sc0) ^ ((sr0 & 7) << 3);

  short8 kst[2], vst[2];
  {
    const int kb = kt0 * 64;
#pragma unroll
    for (int i = 0; i < 2; ++i) {
      const int r = sr0 + i * 32;
      kst[i] = *(const short8*)(kw  + ((size_t)(b * 2048 + kb + r)) * 64 + sc0);
      vst[i] = *(const short8*)(vtw + ((size_t)(b * 64 + r)) * 2048 + kb + sc0);
    }
#pragma unroll
    for (int i = 0; i < 2; ++i) {
      *(short8*)&lK[0][la0 + i * 2048] = kst[i];
      *(short8*)&lV[0][la0 + i * 2048] = vst[i];
    }
  }
  __syncthreads();

  for (int kt = kt0; kt < kt1; ++kt) {
    const int cur = (kt - kt0) & 1;
    if (kt + 1 < kt1) {
      const int kb = (kt + 1) * 64;
#pragma unroll
      for (int i = 0; i < 2; ++i) {
        const int r = sr0 + i * 32;
        kst[i] = *(const short8*)(kw  + ((size_t)(b * 2048 + kb + r)) * 64 + sc0);
        vst[i] = *(const short8*)(vtw + ((size_t)(b * 64 + r)) * 2048 + kb + sc0);
      }
    }
    // QK^T (swapped): s4[c][r] = S[key = 64kt+16c+4lg+r][q = q0r+lr]
    f32x4 s4[4];
#pragma unroll
    for (int c = 0; c < 4; ++c) {
      const int row = 16 * c + lr;
      const short8 kf0 = *(const short8*)&lK[cur][(row * 64 + lg * 8) ^ ((row & 7) << 3)];
      const short8 kf1 = *(const short8*)&lK[cur][(row * 64 + 32 + lg * 8) ^ ((row & 7) << 3)];
      f32x4 z = vzero;
      z = mfma16(kf0, qa, z);
      z = mfma16(kf1, qb, z);
      s4[c] = z;
    }
    if (kt == j) {   // causal mask on the diagonal tile
#pragma unroll
      for (int c = 0; c < 4; ++c)
#pragma unroll
        for (int r = 0; r < 4; ++r)
          if (16 * c + 4 * lg + r > sid * 16 + lr) s4[c][r] = -1e30f;
    }
    // exp2 + lane-local row-sum accumulation
#pragma unroll
    for (int c = 0; c < 4; ++c)
#pragma unroll
      for (int r = 0; r < 4; ++r) {
        const float e = __builtin_amdgcn_exp2f(s4[c][r]);
        s4[c][r] = e;
        lsum += e;
      }
    // pack P lane-locally: pb0 = keys of c=0,1 ; pb1 = keys of c=2,3
    PackU p0, p1;
    p0.u[0] = cvt_pk_bf16(s4[0][0], s4[0][1]);
    p0.u[1] = cvt_pk_bf16(s4[0][2], s4[0][3]);
    p0.u[2] = cvt_pk_bf16(s4[1][0], s4[1][1]);
    p0.u[3] = cvt_pk_bf16(s4[1][2], s4[1][3]);
    p1.u[0] = cvt_pk_bf16(s4[2][0], s4[2][1]);
    p1.u[1] = cvt_pk_bf16(s4[2][2], s4[2][3]);
    p1.u[2] = cvt_pk_bf16(s4[3][0], s4[3][1]);
    p1.u[3] = cvt_pk_bf16(s4[3][2], s4[3][3]);
    const short8 pb0 = p0.s8, pb1 = p1.s8;
    // PV: o[cd] over d = 16cd+4lg+r
#pragma unroll
    for (int cd = 0; cd < 4; ++cd) {
      const int row = 16 * cd + lr;
      const short8 vf0 = *(const short8*)&lV[cur][(row * 64 + lg * 8) ^ ((row & 7) << 3)];
      const short8 vf1 = *(const short8*)&lV[cur][(row * 64 + 32 + lg * 8) ^ ((row & 7) << 3)];
      o[cd] = mfma16(vf0, pb0, o[cd]);
      o[cd] = mfma16(vf1, pb1, o[cd]);
    }
    if (kt + 1 < kt1) {
#pragma unroll
      for (int i = 0; i < 2; ++i) {
        *(short8*)&lK[cur ^ 1][la0 + i * 2048] = kst[i];
        *(short8*)&lV[cur ^ 1][la0 + i * 2048] = vst[i];
      }
      __syncthreads();
    }
  }

  lsum += __shfl_xor(lsum, 16, 64);
  lsum += __shfl_xor(lsum, 32, 64);

  if (nch == 1) {
    const float inv = 1.0f / lsum;
    float* op = out + ((size_t)(b * 2048 + q0r + lr)) * 64;
#pragma unroll
    for (int cd = 0; cd < 4; ++cd) {
      f32x4 v = o[cd] * inv;
      *(f32x4*)(op + 16 * cd + 4 * lg) = v;
    }
  } else {
    int pb;
    if (j < 16)      pb = 2 * (j - 8);
    else if (j < 24) pb = 16 + 3 * (j - 16);
    else             pb = 40 + 4 * (j - 24);
    const int pidx = b * 72 + pb + ch;
    float* op = Opart + ((size_t)(pidx * 64) + sid * 16 + lr) * 64;
#pragma unroll
    for (int cd = 0; cd < 4; ++cd)
      *(f32x4*)(op + 16 * cd + 4 * lg) = o[cd];
    if (lg == 0) lpart[pidx * 64 + sid * 16 + lr] = lsum;
  }
}

// ---------------------------------------------------------------------------
// Merge partials for chunked groups (j >= 8). 768 blocks x 256 thr.
// thread -> (merged q-row, 4-wide d quad); out = sum(Opart)/sum(l).
// ---------------------------------------------------------------------------
__global__ __launch_bounds__(256) void merge_kernel(
    const float* __restrict__ Opart, const float* __restrict__ lpart,
    float* __restrict__ out)
{
  const int t = blockIdx.x * 256 + threadIdx.x;
  const int ridx = t >> 4;           // 0..12287
  const int dq = (t & 15) * 4;
  const int b = ridx / 1536;
  const int r2 = ridx % 1536;
  const int jj = r2 >> 6;            // 0..23 -> j = jj+8
  const int ql = r2 & 63;
  int pb, nch;
  if (jj < 8)       { pb = 2 * jj;            nch = 2; }
  else if (jj < 16) { pb = 16 + 3 * (jj - 8); nch = 3; }
  else              { pb = 40 + 4 * (jj - 16); nch = 4; }
  const int base = b * 72 + pb;
  f32x4 acc = {0.f, 0.f, 0.f, 0.f};
  float l = 0.f;
  for (int c = 0; c < nch; ++c) {
    acc += *(const f32x4*)(Opart + (((size_t)(base + c) * 64 + ql) * 64 + dq));
    l += lpart[(base + c) * 64 + ql];
  }
  const float inv = 1.0f / l;
  *(f32x4*)&out[((size_t)(b * 2048 + (jj + 8) * 64 + ql)) * 64 + dq] = acc * inv;
}

extern "C" void kernel_launch(void* const* d_in, const int* in_sizes, int n_in,
                              void* d_out, int out_size, void* d_ws, size_t ws_size,
                              hipStream_t stream) {
  // setup_inputs order: x, Wk, Wq, Wv
  const float* x  = (const float*)d_in[0];
  const float* Wk = (const float*)d_in[1];
  const float* Wq = (const float*)d_in[2];
  const float* Wv = (const float*)d_in[3];

  u16* wcat = (u16*)d_ws;                        // 192*1024       = 196608
  u16* qw   = wcat + 196608;                     // 16384*64
  u16* kw   = qw + 1048576;
  u16* vtw  = kw + 1048576;
  float* Opart = (float*)(vtw + 1048576);        // 576*64*64 f32
  float* lpart = Opart + 2359296;                // 576*64 f32
  float* out = (float*)d_out;

  wconv_kernel<<<dim3(96),  dim3(256), 0, stream>>>(Wk, Wq, Wv, wcat);
  proj_kernel <<<dim3(256), dim3(512), 0, stream>>>(x, wcat, qw, kw, vtw);
  attn_kernel <<<dim3(640), dim3(256), 0, stream>>>(qw, kw, vtw, out, Opart, lpart);
  merge_kernel<<<dim3(768), dim3(256), 0, stream>>>(Opart, lpart, out);
}